// Round 5
// baseline (335.020 us; speedup 1.0000x reference)
//
#include <hip/hip_runtime.h>

// StainNormalization v5: v3 structure, nontemporal hints REMOVED (A/B isolating nt).
//
// out[d] = min(exp2(sum_c log2(x_c+1e-6) * (M[c][d]*gamma[d]) - beta[d]/ln2), 1)
// (exp2 >= 0 always, so the lower clamp is free)
//
// History: v1 (AoS 48B-stride lanes) ~95us. v2.1 (LDS-transposed coalescing + nt)
// ~81us. v3 (drop barriers, wave-private LDS) ~80us. v4 (persistent + reg-staged
// pipeline) ~84us. Latency/occupancy/barrier theories all falsified by experiment;
// compute and DS have >10x headroom by arithmetic. All ~5.0 TB/s variants share
// one untested variable introduced WITH the coalescing fix: the nontemporal bit
// on every global access. The 6.29 TB/s copy ubench and 6.6 TB/s fills use plain
// accesses. Theory: nt (L2 no-allocate / streaming path) defeats L2 request
// aggregation + write combining -> flat ~20% HBM-efficiency tax, invariant to
// scheduling -- matching all three null results.
//
// v5 = v3 with plain loads/stores. Everything else identical.
//
// Swizzle swz(k) = k + (k>>3) (pad slot per 8): linear-side (k = lane+64i) and
// pixel-side (k = 3*lane+j) b128 accesses each land 8 lanes per bank-group ->
// conflict-free-equivalent (verified: SQ_LDS_BANK_CONFLICT = 0 in v2.1-v4).
// Wave window stride 216 (== 0 mod 8) preserves the structure.
// LDS = 4*216*16B = 13.8 KiB -> 8 blocks/CU (waves-limited).

typedef float f4 __attribute__((ext_vector_type(4)));

constexpr int BLOCK = 256;
constexpr int WSLOTS = 192;                    // float4 slots per wave (64 lanes * 3)
constexpr int WPAD = WSLOTS + WSLOTS / 8;      // 216 with pad slots
constexpr int LDS_SLOTS = 4 * WPAD;            // 864
constexpr int SLOTS = BLOCK * 3;               // 768 float4 slots per block
constexpr int PIXB = 1024;                     // pixels per block

__device__ __forceinline__ int swz(int k) { return k + (k >> 3); }

__global__ __launch_bounds__(BLOCK) void stain_norm_kernel(
    const float* __restrict__ x,
    const float* __restrict__ Mp,     // 3x3 row-major M[c*3+d]
    const float* __restrict__ gp,     // gamma[3]
    const float* __restrict__ bp,     // beta[3]
    float* __restrict__ out,
    int npix, int nfull)
{
    __shared__ f4 lds[LDS_SLOTS];

    // Uniform parameter loads (broadcast, cached)
    const float g0 = gp[0], g1 = gp[1], g2 = gp[2];
    const float A00 = Mp[0] * g0, A01 = Mp[1] * g1, A02 = Mp[2] * g2;
    const float A10 = Mp[3] * g0, A11 = Mp[4] * g1, A12 = Mp[5] * g2;
    const float A20 = Mp[6] * g0, A21 = Mp[7] * g1, A22 = Mp[8] * g2;
    const float INV_LN2 = 1.4426950408889634f;
    const float c0 = -bp[0] * INV_LN2;
    const float c1 = -bp[1] * INV_LN2;
    const float c2 = -bp[2] * INV_LN2;
    const float EPS = 1e-6f;

    const int t    = threadIdx.x;
    const int b    = blockIdx.x;
    const int wid  = t >> 6;
    const int lane = t & 63;

    if (b < nfull) {
        f4* __restrict__ wlds = lds + wid * WPAD;   // wave-private window

        // ---- Phase A: contiguous global load -> swizzled wave-private LDS ----
        const f4* __restrict__ xv =
            reinterpret_cast<const f4*>(x) + (size_t)b * SLOTS + wid * WSLOTS;
#pragma unroll
        for (int i = 0; i < 3; ++i) {
            const int k = lane + i * 64;             // lane-contiguous per instr
            wlds[swz(k)] = xv[k];                    // plain load (no nt)
        }
        // no barrier: same-wave ds_write -> ds_read ordered by lgkmcnt

        // ---- Phase B: gather 4 whole pixels (12 floats) from LDS, compute ----
        float f[12];
#pragma unroll
        for (int j = 0; j < 3; ++j) {
            f4 v = wlds[swz(3 * lane + j)];
            f[4 * j + 0] = v.x; f[4 * j + 1] = v.y;
            f[4 * j + 2] = v.z; f[4 * j + 3] = v.w;
        }

        float o[12];
#pragma unroll
        for (int j = 0; j < 4; ++j) {
            const float l0 = __builtin_amdgcn_logf(f[3 * j + 0] + EPS);
            const float l1 = __builtin_amdgcn_logf(f[3 * j + 1] + EPS);
            const float l2 = __builtin_amdgcn_logf(f[3 * j + 2] + EPS);
            o[3 * j + 0] = fminf(__builtin_amdgcn_exp2f(fmaf(l0, A00, fmaf(l1, A10, fmaf(l2, A20, c0)))), 1.0f);
            o[3 * j + 1] = fminf(__builtin_amdgcn_exp2f(fmaf(l0, A01, fmaf(l1, A11, fmaf(l2, A21, c1)))), 1.0f);
            o[3 * j + 2] = fminf(__builtin_amdgcn_exp2f(fmaf(l0, A02, fmaf(l1, A12, fmaf(l2, A22, c2)))), 1.0f);
        }

        // ---- Phase C: results back to the same slots (same wave, lgkmcnt-ordered) ----
#pragma unroll
        for (int j = 0; j < 3; ++j) {
            f4 v;
            v.x = o[4 * j + 0]; v.y = o[4 * j + 1];
            v.z = o[4 * j + 2]; v.w = o[4 * j + 3];
            wlds[swz(3 * lane + j)] = v;
        }

        // ---- Phase D: swizzled LDS -> contiguous global store ----
        f4* __restrict__ ov =
            reinterpret_cast<f4*>(out) + (size_t)b * SLOTS + wid * WSLOTS;
#pragma unroll
        for (int i = 0; i < 3; ++i) {
            const int k = lane + i * 64;             // lane-contiguous per instr
            ov[k] = wlds[swz(k)];                    // plain store (no nt)
        }
    } else {
        // ---- Tail block: scalar per-pixel (bench shape divides evenly; this is
        // correctness insurance only) ----
        for (int q = nfull * PIXB + t; q < npix; q += BLOCK) {
            const float l0 = __builtin_amdgcn_logf(x[3 * q + 0] + EPS);
            const float l1 = __builtin_amdgcn_logf(x[3 * q + 1] + EPS);
            const float l2 = __builtin_amdgcn_logf(x[3 * q + 2] + EPS);
            out[3 * q + 0] = fminf(__builtin_amdgcn_exp2f(fmaf(l0, A00, fmaf(l1, A10, fmaf(l2, A20, c0)))), 1.0f);
            out[3 * q + 1] = fminf(__builtin_amdgcn_exp2f(fmaf(l0, A01, fmaf(l1, A11, fmaf(l2, A21, c1)))), 1.0f);
            out[3 * q + 2] = fminf(__builtin_amdgcn_exp2f(fmaf(l0, A02, fmaf(l1, A12, fmaf(l2, A22, c2)))), 1.0f);
        }
    }
}

extern "C" void kernel_launch(void* const* d_in, const int* in_sizes, int n_in,
                              void* d_out, int out_size, void* d_ws, size_t ws_size,
                              hipStream_t stream) {
    const float* x     = (const float*)d_in[0];
    const float* M     = (const float*)d_in[1];
    const float* gamma = (const float*)d_in[2];
    const float* beta  = (const float*)d_in[3];
    float* out = (float*)d_out;

    const int n = in_sizes[0];        // total floats (B*H*W*3)
    const int npix = n / 3;           // pixels
    const int nfull = npix / PIXB;    // blocks with 1024 whole pixels
    const int grid = nfull + ((npix % PIXB) ? 1 : 0);

    stain_norm_kernel<<<grid, BLOCK, 0, stream>>>(x, M, gamma, beta, out, npix, nfull);
}